// Round 2
// baseline (336.600 us; speedup 1.0000x reference)
//
#include <hip/hip_runtime.h>

typedef unsigned int u32;

#define DIN 128
#define DH  128
#define SEQL 512
#define NBATCH 256
#define NC  512          // 4*DH fused gate columns
#define TC  64           // timesteps per chunk
#define NCHUNK (SEQL/TC) // 8

typedef __fp16 half2_t __attribute__((ext_vector_type(2)));
typedef __fp16 half8_t __attribute__((ext_vector_type(8)));
typedef float  f32x4   __attribute__((ext_vector_type(4)));

__device__ __forceinline__ u32 pk2(float a, float b) {
  half2_t h = __builtin_amdgcn_cvt_pkrtz(a, b);
  return __builtin_bit_cast(u32, h);
}

__device__ __forceinline__ float dot2(u32 a, u32 b, float c) {
#if defined(__has_builtin) && __has_builtin(__builtin_amdgcn_fdot2)
  return __builtin_amdgcn_fdot2(__builtin_bit_cast(half2_t, a),
                                __builtin_bit_cast(half2_t, b), c, false);
#else
  half2_t ha = __builtin_bit_cast(half2_t, a);
  half2_t hb = __builtin_bit_cast(half2_t, b);
  return c + (float)ha[0]*(float)hb[0] + (float)ha[1]*(float)hb[1];
#endif
}

// Pack fused weight matrices into f16-pair (k-pair) column-major images:
// wxT[j][kk] = (wx[2kk][j], wx[2kk+1][j]),  j in [0,512), kk in [0,64)
__global__ void pack_w(const float* __restrict__ x2i, const float* __restrict__ x2f,
                       const float* __restrict__ x2g, const float* __restrict__ x2o,
                       const float* __restrict__ h2i, const float* __restrict__ h2f,
                       const float* __restrict__ h2g, const float* __restrict__ h2o,
                       u32* __restrict__ wxT, u32* __restrict__ whT) {
  int idx = blockIdx.x * blockDim.x + threadIdx.x;   // 0..32767
  if (idx >= NC * 64) return;
  int j = idx >> 6, kk = idx & 63;
  int g = j >> 7, jj = j & 127;
  const float* wx = (g == 0) ? x2i : (g == 1) ? x2f : (g == 2) ? x2g : x2o;
  const float* wh = (g == 0) ? h2i : (g == 1) ? h2f : (g == 2) ? h2g : h2o;
  wxT[idx] = pk2(wx[(2*kk)*DH + jj], wx[(2*kk+1)*DH + jj]);
  whT[idx] = pk2(wh[(2*kk)*DH + jj], wh[(2*kk+1)*DH + jj]);
}

// LDS layout (dynamic, 82432 B):
//   xs   : [64 t][64 kk] u32, XOR-swizzled (16 KB)      offset 0
//   xg   : [16 tq][512 col][4 r] f16 (64 KB)            offset 16384
//   hbuf : [2][64] u32 (h as f16 pairs, 512 B)          offset 81920
__global__ __launch_bounds__(512, 2) void lstm_fused(
    const float* __restrict__ x, const u32* __restrict__ wxT,
    const u32* __restrict__ whT, const float* __restrict__ w_out,
    float* __restrict__ out) {
  extern __shared__ char lds[];
  u32*    xs   = (u32*)lds;
  __fp16* xg   = (__fp16*)(lds + 16384);
  u32*    xg_u = (u32*)xg;
  u32*    hbuf = (u32*)(lds + 16384 + 65536);

  const int tid = threadIdx.x;
  const int b   = blockIdx.x;
  const int l   = tid & 63, wv = tid >> 6;   // lane, wave
  const int q   = l >> 4;                    // gate id: 0=i 1=f 2=g 3=o
  const int jj  = l & 15;
  const int col = q * DH + wv * 16 + jj;     // fused gate column owned by thread

  // wh column into registers (f16 pairs): 64 regs, persistent
  uint4 wc[16];
  {
    const uint4* whp = (const uint4*)(whT + col * 64);
#pragma unroll
    for (int m = 0; m < 16; ++m) wc[m] = whp[m];
  }

  if (tid < 128) hbuf[tid] = 0u;   // zero both h buffers (h0 = 0)
  float c = 0.f;
  int p = 0;
  const float* xb = x + (size_t)b * SEQL * DIN;

  __syncthreads();

  for (int ch = 0; ch < NCHUNK; ++ch) {
    // ---- stage x chunk -> xs (f16 pairs, XOR bank-swizzle) ----
    {
      const float4* xv = (const float4*)(xb + (size_t)ch * TC * DIN);
#pragma unroll
      for (int i = 0; i < 4; ++i) {
        int idx = tid + i * 512;          // 0..2047 float4s
        float4 v = xv[idx];
        int t = idx >> 5, kq = idx & 31;  // row t, float4-within-row
        int blk = kq >> 1;                // 16B block index (kk>>2)
        int base = t * 64 + ((blk ^ (t & 15)) << 2) + ((kq & 1) << 1);
        xs[base]     = pk2(v.x, v.y);
        xs[base + 1] = pk2(v.z, v.w);
      }
    }
    __syncthreads();

    // ---- phase A: xg[t][col] = x_chunk @ wx  via 16x16x32 f16 MFMA ----
    {
      const int kg = l >> 4, r15 = l & 15;
#pragma unroll
      for (int nt = 0; nt < 4; ++nt) {
        int n = wv * 64 + nt * 16 + r15;
        uint4 bf[4];
#pragma unroll
        for (int ko = 0; ko < 4; ++ko)
          bf[ko] = *(const uint4*)(wxT + n * 64 + ko * 16 + kg * 4);
#pragma unroll
        for (int tt = 0; tt < 4; ++tt) {
          f32x4 acc = {0.f, 0.f, 0.f, 0.f};
          int tA = tt * 16 + r15;
#pragma unroll
          for (int ko = 0; ko < 4; ++ko) {
            int blk = ko * 4 + kg;
            uint4 av = *(const uint4*)(xs + tA * 64 + ((blk ^ r15) << 2));
            acc = __builtin_amdgcn_mfma_f32_16x16x32_f16(
                __builtin_bit_cast(half8_t, av),
                __builtin_bit_cast(half8_t, bf[ko]), acc, 0, 0, 0);
          }
          // C mapping: col = n (lane&15), rows t = tt*16 + kg*4 + r
          int tq = tt * 4 + kg;
          uint2 pkd;
          pkd.x = pk2(acc[0], acc[1]);
          pkd.y = pk2(acc[2], acc[3]);
          *(uint2*)(xg_u + (tq * NC + n) * 2) = pkd;
        }
      }
    }
    __syncthreads();

    // ---- phase B: 64 sequential recurrence steps ----
    for (int s = 0; s < TC; ++s) {
      uint4 hv[16];
      {
        const uint4* hb4 = (const uint4*)(hbuf + p * 64);
#pragma unroll
        for (int m = 0; m < 16; ++m) hv[m] = hb4[m];
      }
      float a0 = (float)xg[((s >> 2) * NC + col) * 4 + (s & 3)];
      float a1 = 0.f;
#pragma unroll
      for (int m = 0; m < 16; ++m) {
        a0 = dot2(wc[m].x, hv[m].x, a0);
        a1 = dot2(wc[m].y, hv[m].y, a1);
        a0 = dot2(wc[m].z, hv[m].z, a0);
        a1 = dot2(wc[m].w, hv[m].w, a1);
      }
      float gate = a0 + a1;
      // i,f,o: sigmoid ; g: tanh = 2*sigmoid(2x)-1  (branchless per-lane)
      float mm  = (q == 2) ? 2.f : 1.f;
      float e   = __expf(-(mm * gate));
      float y   = __builtin_amdgcn_rcpf(1.f + e);
      float val = (q == 2) ? (2.f * y - 1.f) : y;

      float f = __shfl_down(val, 16, 64);   // valid on q==0 lanes
      float g = __shfl_down(val, 32, 64);
      float o = __shfl_down(val, 48, 64);
      c = __builtin_fmaf(f, c, val * g);    // c = f*c + i*g   (val = i on q0)
      float e2 = __expf(-2.f * c);
      float th = __builtin_fmaf(2.f, __builtin_amdgcn_rcpf(1.f + e2), -1.f);
      float hval = o * th;
      if (l < 16) {                          // q0 lanes own h[j], j = wv*16 + l
        __fp16* hdst = (__fp16*)(hbuf + (p ^ 1) * 64);
        hdst[wv * 16 + l] = (__fp16)hval;
      }
      p ^= 1;
      __syncthreads();
    }
  }

  // ---- tail: out[b][n] = h_final @ w_out ----
  if (tid < DH) {
    int n = tid;
    const u32* hf = hbuf + p * 64;
    float acc = 0.f;
#pragma unroll 8
    for (int kk = 0; kk < 64; ++kk) {
      half2_t h2 = __builtin_bit_cast(half2_t, hf[kk]);
      acc = __builtin_fmaf((float)h2[0], w_out[(2*kk)*DH + n],
            __builtin_fmaf((float)h2[1], w_out[(2*kk+1)*DH + n], acc));
    }
    out[b * DH + n] = acc;
  }
}

extern "C" void kernel_launch(void* const* d_in, const int* in_sizes, int n_in,
                              void* d_out, int out_size, void* d_ws, size_t ws_size,
                              hipStream_t stream) {
  const float* x    = (const float*)d_in[0];
  const float* x2i  = (const float*)d_in[1];
  const float* x2f  = (const float*)d_in[2];
  const float* x2g  = (const float*)d_in[3];
  const float* x2o  = (const float*)d_in[4];
  const float* h2i  = (const float*)d_in[5];
  const float* h2f  = (const float*)d_in[6];
  const float* h2g  = (const float*)d_in[7];
  const float* h2o  = (const float*)d_in[8];
  const float* wout = (const float*)d_in[9];

  u32* wxT = (u32*)d_ws;            // 512*64*4 = 128 KB
  u32* whT = wxT + NC * 64;         // +128 KB

  (void)hipFuncSetAttribute((const void*)lstm_fused,
                            hipFuncAttributeMaxDynamicSharedMemorySize, 82432);

  pack_w<<<64, 512, 0, stream>>>(x2i, x2f, x2g, x2o, h2i, h2f, h2g, h2o, wxT, whT);
  lstm_fused<<<NBATCH, 512, 82432, stream>>>(x, wxT, whT, wout, (float*)d_out);
}

// Round 3
// 319.655 us; speedup vs baseline: 1.0530x; 1.0530x over previous
//
#include <hip/hip_runtime.h>

typedef unsigned int u32;
typedef __fp16 half2_t __attribute__((ext_vector_type(2)));
typedef __fp16 half8_t __attribute__((ext_vector_type(8)));
typedef float  f32x4   __attribute__((ext_vector_type(4)));

#define DIN 128
#define DH  128
#define SEQL 512
#define NBATCH 256
#define NC  512          // 4*DH fused gate columns
#define TC  64           // timesteps per chunk
#define NCHUNK (SEQL/TC) // 8

#define LDS_HOFF 65536   // hbuf byte offset (xgT = 64 KB below it)
#define LDS_TOTAL (65536 + 512)

__device__ __forceinline__ u32 pk2(float a, float b) {
  half2_t h = __builtin_amdgcn_cvt_pkrtz(a, b);
  return __builtin_bit_cast(u32, h);
}

__device__ __forceinline__ float dot2(u32 a, u32 b, float c) {
#if defined(__has_builtin) && __has_builtin(__builtin_amdgcn_fdot2)
  return __builtin_amdgcn_fdot2(__builtin_bit_cast(half2_t, a),
                                __builtin_bit_cast(half2_t, b), c, false);
#else
  half2_t ha = __builtin_bit_cast(half2_t, a);
  half2_t hb = __builtin_bit_cast(half2_t, b);
  return c + (float)ha[0]*(float)hb[0] + (float)ha[1]*(float)hb[1];
#endif
}

#if defined(__has_builtin) && __has_builtin(__builtin_amdgcn_update_dpp)
__device__ __forceinline__ float qp_xor1(float v) {   // quad_perm [1,0,3,2]
  return __builtin_bit_cast(float,
      __builtin_amdgcn_update_dpp(0, __builtin_bit_cast(int, v), 0xB1, 0xF, 0xF, true));
}
__device__ __forceinline__ float qp_xor2(float v) {   // quad_perm [2,3,0,1]
  return __builtin_bit_cast(float,
      __builtin_amdgcn_update_dpp(0, __builtin_bit_cast(int, v), 0x4E, 0xF, 0xF, true));
}
#else
__device__ __forceinline__ float qp_xor1(float v) { return __shfl_xor(v, 1, 64); }
__device__ __forceinline__ float qp_xor2(float v) { return __shfl_xor(v, 2, 64); }
#endif

__device__ __forceinline__ float fexp2(float x) {
#if defined(__has_builtin) && __has_builtin(__builtin_amdgcn_exp2f)
  return __builtin_amdgcn_exp2f(x);
#else
  return __builtin_exp2f(x);
#endif
}

#define DOT16(S, W, H0, H1, H2, H3) \
  S = dot2((W)[0].x, (H0).x, S); S = dot2((W)[0].y, (H0).y, S); \
  S = dot2((W)[0].z, (H0).z, S); S = dot2((W)[0].w, (H0).w, S); \
  S = dot2((W)[1].x, (H1).x, S); S = dot2((W)[1].y, (H1).y, S); \
  S = dot2((W)[1].z, (H1).z, S); S = dot2((W)[1].w, (H1).w, S); \
  S = dot2((W)[2].x, (H2).x, S); S = dot2((W)[2].y, (H2).y, S); \
  S = dot2((W)[2].z, (H2).z, S); S = dot2((W)[2].w, (H2).w, S); \
  S = dot2((W)[3].x, (H3).x, S); S = dot2((W)[3].y, (H3).y, S); \
  S = dot2((W)[3].z, (H3).z, S); S = dot2((W)[3].w, (H3).w, S);

// Pack fused weight matrices into f16-pair (k-pair) column-major images:
// wxT[j][kk] = (wx[2kk][j], wx[2kk+1][j]),  j in [0,512), kk in [0,64)
__global__ void pack_w(const float* __restrict__ x2i, const float* __restrict__ x2f,
                       const float* __restrict__ x2g, const float* __restrict__ x2o,
                       const float* __restrict__ h2i, const float* __restrict__ h2f,
                       const float* __restrict__ h2g, const float* __restrict__ h2o,
                       u32* __restrict__ wxT, u32* __restrict__ whT) {
  int idx = blockIdx.x * blockDim.x + threadIdx.x;   // 0..32767
  if (idx >= NC * 64) return;
  int j = idx >> 6, kk = idx & 63;
  int g = j >> 7, jjj = j & 127;
  const float* wx = (g == 0) ? x2i : (g == 1) ? x2f : (g == 2) ? x2g : x2o;
  const float* wh = (g == 0) ? h2i : (g == 1) ? h2f : (g == 2) ? h2g : h2o;
  wxT[idx] = pk2(wx[(2*kk)*DH + jjj], wx[(2*kk+1)*DH + jjj]);
  whT[idx] = pk2(wh[(2*kk)*DH + jjj], wh[(2*kk+1)*DH + jjj]);
}

// LDS: xgT [512 col][128 B of t, XOR-swizzled f16] = 64 KB ; hbuf [2][64] u32
__global__ __launch_bounds__(512, 2) void lstm_fused(
    const float* __restrict__ x, const u32* __restrict__ wxT,
    const u32* __restrict__ whT, const float* __restrict__ w_out,
    float* __restrict__ out) {
  extern __shared__ char lds[];
  char* xgT  = lds;
  u32*  hbuf = (u32*)(lds + LDS_HOFF);

  const int tid = threadIdx.x;
  const int b   = blockIdx.x;
  const int l   = tid & 63, wv = tid >> 6;
  // phase-B coords: quad member kq (k-split), jj hidden-offset
  const int kq  = l & 3, jj = l >> 2;
  const int colB = kq * DH + wv * 16 + jj;   // this lane's xg gate-column
  const int j    = wv * 16 + jj;             // hidden index owned by quad
  // phase-A coords
  const int kg = l >> 4, r15 = l & 15;

  // phase-B weights: wq[q][mm] = whT[q*128 + j][16*kq + mm*4 .. +4]
  uint4 wq[4][4];
#pragma unroll
  for (int q = 0; q < 4; ++q) {
    const uint4* wp = (const uint4*)(whT + (q * DH + j) * 64 + kq * 16);
#pragma unroll
    for (int mm = 0; mm < 4; ++mm) wq[q][mm] = wp[mm];
  }

  if (tid < 128) hbuf[tid] = 0u;   // zero both h buffers
  float c = 0.f;
  u32 rdoff = LDS_HOFF + kq * 64;        // read h buf 0 first
  u32 wroff = LDS_HOFF + 256 + j * 2;    // write h buf 1 first
  const bool isG = (kq == 2);
  const float mexp = isG ? -2.885390082f : -1.442695041f;  // exp2 multipliers
  const bool k1 = (kq & 1) != 0, k2 = (kq & 2) != 0;

  const float* xb = x + (size_t)b * SEQL * DIN;
  __syncthreads();

  for (int ch = 0; ch < NCHUNK; ++ch) {
    // ---- phase A: xg[t][col] = x_chunk @ wx via MFMA, A-frags from global ----
#pragma unroll 1
    for (int tt = 0; tt < 4; ++tt) {
      uint4 afr[4];
#pragma unroll
      for (int ko = 0; ko < 4; ++ko) {
        const float4* xp = (const float4*)(xb + (size_t)(ch*TC + tt*16 + r15)*DIN + ko*32 + kg*8);
        float4 v0 = xp[0], v1 = xp[1];
        afr[ko].x = pk2(v0.x, v0.y); afr[ko].y = pk2(v0.z, v0.w);
        afr[ko].z = pk2(v1.x, v1.y); afr[ko].w = pk2(v1.z, v1.w);
      }
#pragma unroll
      for (int nt = 0; nt < 4; ++nt) {
        int n = wv * 64 + nt * 16 + r15;
        f32x4 acc = {0.f, 0.f, 0.f, 0.f};
#pragma unroll
        for (int ko = 0; ko < 4; ++ko) {
          uint4 bf = *(const uint4*)(wxT + n*64 + ko*16 + kg*4);
          acc = __builtin_amdgcn_mfma_f32_16x16x32_f16(
              __builtin_bit_cast(half8_t, afr[ko]),
              __builtin_bit_cast(half8_t, bf), acc, 0, 0, 0);
        }
        // store C: col n, t0 = tt*16+kg*4 .. +4, into [col][t] XOR-swizzled
        int t0 = tt*16 + kg*4;
        u32 off = (u32)(n*128 + ((t0*2) ^ ((n & 7) << 4)));
        uint2 pw; pw.x = pk2(acc[0], acc[1]); pw.y = pk2(acc[2], acc[3]);
        *(uint2*)(xgT + off) = pw;
      }
    }
    __syncthreads();

    // ---- phase B: 64 sequential steps, k-split=4 over DPP quads ----
#pragma unroll 1
    for (int m = 0; m < 8; ++m) {
      uint4 xgv = *(const uint4*)(xgT + colB*128 + ((m*16) ^ ((colB & 7) << 4)));
      half8_t xgh = __builtin_bit_cast(half8_t, xgv);
#pragma unroll
      for (int s8 = 0; s8 < 8; ++s8) {
        uint4 h0 = *(const uint4*)(lds + rdoff);
        uint4 h1 = *(const uint4*)(lds + rdoff + 16);
        uint4 h2 = *(const uint4*)(lds + rdoff + 32);
        uint4 h3 = *(const uint4*)(lds + rdoff + 48);
        float s0 = 0.f, s1 = 0.f, s2 = 0.f, s3 = 0.f;
        DOT16(s0, wq[0], h0, h1, h2, h3)
        DOT16(s1, wq[1], h0, h1, h2, h3)
        DOT16(s2, wq[2], h0, h1, h2, h3)
        DOT16(s3, wq[3], h0, h1, h2, h3)
        // quad reduction (each lane ends with all-k sums, identical in quad)
        s0 += qp_xor1(s0); s0 += qp_xor2(s0);
        s1 += qp_xor1(s1); s1 += qp_xor2(s1);
        s2 += qp_xor1(s2); s2 += qp_xor2(s2);
        s3 += qp_xor1(s3); s3 += qp_xor2(s3);
        // this lane's gate (q = kq): total + its xg, then nonlinearity
        float t01 = k1 ? s1 : s0;
        float t23 = k1 ? s3 : s2;
        float tk  = (k2 ? t23 : t01) + (float)xgh[s8];
        float e   = fexp2(tk * mexp);
        float y   = __builtin_amdgcn_rcpf(1.f + e);
        float val = isG ? __builtin_fmaf(2.f, y, -1.f) : y;   // tanh for g
        // quad all-gather: (i,f,g,o) into every lane
        float vb = qp_xor1(val);
        float x0 = k1 ? vb : val;    // gate 2m   (m = kq>>1)
        float x1 = k1 ? val : vb;    // gate 2m+1
        float y2 = qp_xor2(x0);
        float y3 = qp_xor2(x1);
        float gi = k2 ? y2 : x0;
        float gf = k2 ? y3 : x1;
        float gg = k2 ? x0 : y2;
        float go = k2 ? x1 : y3;
        c = __builtin_fmaf(gf, c, gi * gg);
        float e2 = fexp2(c * -2.885390082f);
        float th = __builtin_fmaf(2.f, __builtin_amdgcn_rcpf(1.f + e2), -1.f);
        float hval = go * th;
        if (kq == 0) *(__fp16*)(lds + wroff) = (__fp16)hval;
        rdoff ^= 256; wroff ^= 256;
        __syncthreads();
      }
    }
  }

  // ---- tail: out[b][n] = h_final @ w_out ----
  if (tid < DH) {
    int n = tid;
    const u32* hf = (const u32*)(lds + (rdoff & ~(u32)255));  // current h buffer
    float acc = 0.f;
#pragma unroll 8
    for (int kk = 0; kk < 64; ++kk) {
      half2_t h2v = __builtin_bit_cast(half2_t, hf[kk]);
      acc = __builtin_fmaf((float)h2v[0], w_out[(2*kk)*DH + n],
            __builtin_fmaf((float)h2v[1], w_out[(2*kk+1)*DH + n], acc));
    }
    out[b * DH + n] = acc;
  }
}

extern "C" void kernel_launch(void* const* d_in, const int* in_sizes, int n_in,
                              void* d_out, int out_size, void* d_ws, size_t ws_size,
                              hipStream_t stream) {
  const float* x    = (const float*)d_in[0];
  const float* x2i  = (const float*)d_in[1];
  const float* x2f  = (const float*)d_in[2];
  const float* x2g  = (const float*)d_in[3];
  const float* x2o  = (const float*)d_in[4];
  const float* h2i  = (const float*)d_in[5];
  const float* h2f  = (const float*)d_in[6];
  const float* h2g  = (const float*)d_in[7];
  const float* h2o  = (const float*)d_in[8];
  const float* wout = (const float*)d_in[9];

  u32* wxT = (u32*)d_ws;            // 512*64*4 = 128 KB
  u32* whT = wxT + NC * 64;         // +128 KB

  (void)hipFuncSetAttribute((const void*)lstm_fused,
                            hipFuncAttributeMaxDynamicSharedMemorySize, LDS_TOTAL);

  pack_w<<<64, 512, 0, stream>>>(x2i, x2f, x2g, x2o, h2i, h2f, h2g, h2o, wxT, whT);
  lstm_fused<<<NBATCH, 512, LDS_TOTAL, stream>>>(x, wxT, whT, wout, (float*)d_out);
}